// Round 1
// baseline (485.445 us; speedup 1.0000x reference)
//
#include <hip/hip_runtime.h>
#include <hip/hip_bf16.h>
#include <math.h>

#define BATCH 2
#define NPT   8192
#define DIMC  128
#define NH    4
#define HDIM  32
#define KNN_K 16
#define HID   32
#define BN    (BATCH*NPT)   // 16384

// ---------------------------------------------------------------------------
// Kernel 1: exact 16-NN by squared distance.
// One wave owns 16 queries. Candidates are processed 64 per step (one per
// lane) from an LDS-staged tile. Each query's running top-16 is stored
// DISTRIBUTED across lanes 0..15 (sorted ascending). A candidate only enters
// the (rare) insert path via a uniform ballot; the insert itself is a
// wave-wide shift via shfl_up — O(1) cost independent of insert position.
// Distance formula replicates numpy bit-for-bit order: sq_i + sq_j - 2*dot,
// no FMA contraction, so tie decisions match jax.lax.top_k (lower index wins
// on equality via strictly-less comparisons).
// ---------------------------------------------------------------------------
#define TILE 2048

__global__ __launch_bounds__(256) void knn_kernel(const float* __restrict__ xyz,
                                                  int* __restrict__ knn_out) {
  __shared__ float4 spts[TILE];   // x,y,z,sq per candidate
  const int tid  = threadIdx.x;
  const int lane = tid & 63;
  const int wave = tid >> 6;
  const int qbase = blockIdx.x * 64 + wave * 16;   // flat query base [0, BN)
  const int b = qbase / NPT;

  float qx[16], qy[16], qz[16], qsq[16];
  float topd[16]; int topi[16]; float tau[16];
#pragma unroll
  for (int qi = 0; qi < 16; ++qi) {
    const int g = qbase + qi;
    qx[qi] = xyz[(size_t)g*3+0];
    qy[qi] = xyz[(size_t)g*3+1];
    qz[qi] = xyz[(size_t)g*3+2];
    qsq[qi] = __fadd_rn(__fadd_rn(__fmul_rn(qx[qi],qx[qi]),
                                  __fmul_rn(qy[qi],qy[qi])),
                        __fmul_rn(qz[qi],qz[qi]));
    topd[qi] = 3e38f; topi[qi] = 0; tau[qi] = 3e38f;
  }

  for (int t = 0; t < NPT/TILE; ++t) {
    __syncthreads();
    // coalesced load of TILE points (3 floats each) into float4 slots
    const float* src = xyz + (size_t)(b*NPT + t*TILE)*3;
    float* sraw = (float*)spts;
    for (int f = tid; f < TILE*3; f += 256) {
      int p = f/3, c = f - p*3;
      sraw[p*4 + c] = src[f];
    }
    __syncthreads();
    for (int i = tid; i < TILE; i += 256) {
      float4 v = spts[i];
      spts[i].w = __fadd_rn(__fadd_rn(__fmul_rn(v.x,v.x), __fmul_rn(v.y,v.y)),
                            __fmul_rn(v.z,v.z));
    }
    __syncthreads();

    for (int c = 0; c < TILE/64; ++c) {
      const float4 cd = spts[c*64 + lane];
      const int cbase = t*TILE + c*64;
#pragma unroll
      for (int qi = 0; qi < 16; ++qi) {
        float dot = __fadd_rn(__fadd_rn(__fmul_rn(qx[qi],cd.x),
                                        __fmul_rn(qy[qi],cd.y)),
                              __fmul_rn(qz[qi],cd.z));
        float d2 = __fsub_rn(__fadd_rn(qsq[qi], cd.w), __fmul_rn(2.0f, dot));
        unsigned long long m = __ballot(d2 < tau[qi]);
        while (m) {
          const int l = __builtin_ctzll(m);
          m &= (m - 1);
          const float dn = __shfl(d2, l);
          const int   ni_ = cbase + l;
          const float my  = topd[qi];
          const int   myi = topi[qi];
          float ab  = __shfl_up(my, 1);
          int   abi = __shfl_up(myi, 1);
          if (lane == 0) ab = -3e38f;
          const bool ge = dn < my;   // insert at or before this position
          const bool gt = dn < ab;   // insert strictly before -> shift down
          topd[qi] = ge ? (gt ? ab  : dn ) : my;
          topi[qi] = ge ? (gt ? abi : ni_) : myi;
          tau[qi] = __shfl(topd[qi], 15);
        }
      }
    }
  }

#pragma unroll
  for (int qi = 0; qi < 16; ++qi) {
    if (lane < KNN_K) knn_out[(size_t)(qbase + qi)*KNN_K + lane] = topi[qi];
  }
}

// ---------------------------------------------------------------------------
// Kernel 2: fused Q/K/V projection. 16 rows per block staged in LDS; each
// thread owns one (row, col) and accumulates all three matrices so the LDS
// read of x is amortized 3x. W column reads are coalesced across the wave.
// ---------------------------------------------------------------------------
__global__ __launch_bounds__(256) void qkv_kernel(const float* __restrict__ x,
    const float* __restrict__ Wq, const float* __restrict__ bq,
    const float* __restrict__ Wk, const float* __restrict__ bk,
    const float* __restrict__ Wv, const float* __restrict__ bv,
    float* __restrict__ q, float* __restrict__ k, float* __restrict__ v) {
  __shared__ float xs[16*DIMC];
  const int tid = threadIdx.x;
  const int rowbase = blockIdx.x * 16;
  for (int i = tid; i < 16*DIMC; i += 256) xs[i] = x[(size_t)rowbase*DIMC + i];
  __syncthreads();
  for (int o = tid; o < 16*DIMC; o += 256) {
    const int r = o >> 7, cc = o & 127;
    float aq = bq[cc], ak = bk[cc], av = bv[cc];
    const float* xr = xs + r*DIMC;
#pragma unroll 4
    for (int kk = 0; kk < DIMC; ++kk) {
      const float xv = xr[kk];
      aq = fmaf(xv, Wq[kk*DIMC+cc], aq);
      ak = fmaf(xv, Wk[kk*DIMC+cc], ak);
      av = fmaf(xv, Wv[kk*DIMC+cc], av);
    }
    const size_t oo = (size_t)(rowbase + r)*DIMC + cc;
    q[oo] = aq; k[oo] = ak; v[oo] = av;
  }
}

// ---------------------------------------------------------------------------
// Kernel 3: gather + bias MLP + 4-head/16-neighbor attention.
// 128 threads per point (2 points per 256-block); thread = channel d.
// Each 32-lane group is exactly one head: the QK dot is a width-32
// shfl_xor reduction, softmax is fully register-replicated per lane.
// ---------------------------------------------------------------------------
__global__ __launch_bounds__(256) void attn_kernel(const float* __restrict__ xyz,
    const int* __restrict__ knn, const float* __restrict__ qb,
    const float* __restrict__ kb, const float* __restrict__ vb,
    const float* __restrict__ W1, const float* __restrict__ b1,
    const float* __restrict__ W2, const float* __restrict__ b2,
    float* __restrict__ ao) {
  __shared__ float sbias[2][NH][KNN_K];
  const int tid = threadIdx.x;
  const int pt  = tid >> 7;          // 0..1
  const int d   = tid & 127;         // channel
  const int h   = d >> 5;            // head
  const int p   = blockIdx.x * 2 + pt;
  const int b   = p / NPT;

  int nidx[KNN_K];
#pragma unroll
  for (int j = 0; j < KNN_K; ++j) nidx[j] = knn[(size_t)p*KNN_K + j];

  // bias MLP: 64 threads per point cover (h2, j2)
  if (d < 64) {
    const int h2 = d >> 4, j2 = d & 15;
    const float qx0 = xyz[(size_t)p*3+0];
    const float qy0 = xyz[(size_t)p*3+1];
    const float qz0 = xyz[(size_t)p*3+2];
    const size_t nn = (size_t)(b*NPT + nidx[j2]);
    const float rx = qx0 - xyz[nn*3+0];
    const float ry = qy0 - xyz[nn*3+1];
    const float rz = qz0 - xyz[nn*3+2];
    float acc = b2[h2];
#pragma unroll 4
    for (int u = 0; u < HID; ++u) {
      float hv = rx*W1[0*HID+u] + ry*W1[1*HID+u] + rz*W1[2*HID+u] + b1[u];
      hv = hv > 0.f ? hv : 0.f;
      acc = fmaf(hv, W2[u*NH + h2], acc);
    }
    sbias[pt][h2][j2] = acc;
  }

  const float qd = qb[(size_t)p*DIMC + d];
  float s[KNN_K], vr[KNN_K];
#pragma unroll
  for (int j = 0; j < KNN_K; ++j) {
    const size_t row = ((size_t)(b*NPT + nidx[j]))*DIMC + d;
    float t = qd * kb[row];
    vr[j] = vb[row];
    t += __shfl_xor(t, 1, 32);
    t += __shfl_xor(t, 2, 32);
    t += __shfl_xor(t, 4, 32);
    t += __shfl_xor(t, 8, 32);
    t += __shfl_xor(t, 16, 32);
    s[j] = t;
  }
  __syncthreads();

  const float sc = 0.17677669529663689f; // 1/sqrt(32)
  float mx = -3e38f;
#pragma unroll
  for (int j = 0; j < KNN_K; ++j) {
    s[j] = s[j]*sc + sbias[pt][h][j];
    mx = fmaxf(mx, s[j]);
  }
  float sum = 0.f;
#pragma unroll
  for (int j = 0; j < KNN_K; ++j) { s[j] = expf(s[j]-mx); sum += s[j]; }
  const float inv = 1.f / sum;
  float out = 0.f;
#pragma unroll
  for (int j = 0; j < KNN_K; ++j) out = fmaf(s[j]*inv, vr[j], out);
  ao[(size_t)p*DIMC + d] = out;
}

// ---------------------------------------------------------------------------
// Kernel 4: output projection, IN-PLACE on d_out. Each block stages its own
// 16 rows to LDS before overwriting exactly those rows — no cross-block
// hazard, deterministic.
// ---------------------------------------------------------------------------
__global__ __launch_bounds__(256) void proj_kernel(float* __restrict__ inout,
    const float* __restrict__ Wo, const float* __restrict__ bo) {
  __shared__ float xs[16*DIMC];
  const int tid = threadIdx.x;
  const int rowbase = blockIdx.x * 16;
  for (int i = tid; i < 16*DIMC; i += 256) xs[i] = inout[(size_t)rowbase*DIMC + i];
  __syncthreads();
  for (int o = tid; o < 16*DIMC; o += 256) {
    const int r = o >> 7, cc = o & 127;
    float a = bo[cc];
    const float* xr = xs + r*DIMC;
#pragma unroll 4
    for (int kk = 0; kk < DIMC; ++kk) a = fmaf(xr[kk], Wo[kk*DIMC+cc], a);
    inout[(size_t)(rowbase + r)*DIMC + cc] = a;
  }
}

// ---------------------------------------------------------------------------
extern "C" void kernel_launch(void* const* d_in, const int* in_sizes, int n_in,
                              void* d_out, int out_size, void* d_ws, size_t ws_size,
                              hipStream_t stream) {
  const float* x   = (const float*)d_in[0];
  const float* xyz = (const float*)d_in[1];
  const float* Wq  = (const float*)d_in[2];
  const float* bq  = (const float*)d_in[3];
  const float* Wk  = (const float*)d_in[4];
  const float* bk  = (const float*)d_in[5];
  const float* Wv  = (const float*)d_in[6];
  const float* bv  = (const float*)d_in[7];
  const float* Wo  = (const float*)d_in[8];
  const float* bo  = (const float*)d_in[9];
  const float* W1  = (const float*)d_in[10];
  const float* b1  = (const float*)d_in[11];
  const float* W2  = (const float*)d_in[12];
  const float* b2  = (const float*)d_in[13];
  float* out = (float*)d_out;

  // workspace layout (bytes): knn idx 1MB | q 8MB | k 8MB | v 8MB  => 25MB
  char* ws = (char*)d_ws;
  int*   knn = (int*)ws;
  float* q   = (float*)(ws + (size_t)(1u<<20));
  float* k   = (float*)(ws + (size_t)9*(1u<<20));
  float* v   = (float*)(ws + (size_t)17*(1u<<20));

  hipLaunchKernelGGL(knn_kernel, dim3(BN/64), dim3(256), 0, stream, xyz, knn);
  hipLaunchKernelGGL(qkv_kernel, dim3(BN/16), dim3(256), 0, stream,
                     x, Wq, bq, Wk, bk, Wv, bv, q, k, v);
  hipLaunchKernelGGL(attn_kernel, dim3(BN/2), dim3(256), 0, stream,
                     xyz, knn, q, k, v, W1, b1, W2, b2, out);
  hipLaunchKernelGGL(proj_kernel, dim3(BN/16), dim3(256), 0, stream,
                     out, Wo, bo);
}

// Round 3
// 328.162 us; speedup vs baseline: 1.4793x; 1.4793x over previous
//
#include <hip/hip_runtime.h>
#include <hip/hip_bf16.h>
#include <math.h>

#define BATCH 2
#define NPT   8192
#define DIMC  128
#define NH    4
#define HDIM  32
#define KNN_K 16
#define HID   32
#define BN    (BATCH*NPT)   // 16384

// ---------------------------------------------------------------------------
// Kernel 1: exact 16-NN by squared distance.
// One wave owns QPW queries (QPW=2 -> 2048 blocks -> 8 blocks/CU -> 8
// waves/SIMD, vs 1 wave/SIMD at QPW=16 which left the insert path's serial
// shfl/ballot chains unhidden: Occupancy 11%, VALUBusy 21%).
// Candidates are processed 64 per step (one per lane) from an LDS-staged
// tile. Each query's running top-16 is stored DISTRIBUTED across lanes
// 0..15 (sorted ascending). A candidate only enters the (rare) insert path
// via a uniform ballot; the insert itself is a wave-wide shift via shfl_up
// — O(1) cost independent of insert position.
// Distance formula replicates numpy bit-for-bit order: sq_i + sq_j - 2*dot,
// no FMA contraction, so tie decisions match jax.lax.top_k (lower index
// wins on equality via strictly-less comparisons).
// ---------------------------------------------------------------------------
#define TILE 1024
#define QPW  2
#define NWV  4

__global__ __launch_bounds__(256) void knn_kernel(const float* __restrict__ xyz,
                                                  int* __restrict__ knn_out) {
  __shared__ float4 spts[TILE];   // x,y,z,sq per candidate (16 KB)
  const int tid  = threadIdx.x;
  const int lane = tid & 63;
  const int wave = tid >> 6;
  const int qbase = blockIdx.x * (NWV*QPW) + wave * QPW;  // flat query base
  const int b = qbase / NPT;

  float qx[QPW], qy[QPW], qz[QPW], qsq[QPW];
  float topd[QPW]; int topi[QPW]; float tau[QPW];
#pragma unroll
  for (int qi = 0; qi < QPW; ++qi) {
    const int g = qbase + qi;
    qx[qi] = xyz[(size_t)g*3+0];
    qy[qi] = xyz[(size_t)g*3+1];
    qz[qi] = xyz[(size_t)g*3+2];
    qsq[qi] = __fadd_rn(__fadd_rn(__fmul_rn(qx[qi],qx[qi]),
                                  __fmul_rn(qy[qi],qy[qi])),
                        __fmul_rn(qz[qi],qz[qi]));
    topd[qi] = 3e38f; topi[qi] = 0; tau[qi] = 3e38f;
  }

  for (int t = 0; t < NPT/TILE; ++t) {
    __syncthreads();
    // coalesced load of TILE points (3 floats each) into float4 slots
    const float* src = xyz + (size_t)(b*NPT + t*TILE)*3;
    float* sraw = (float*)spts;
    for (int f = tid; f < TILE*3; f += 256) {
      int p = f/3, c = f - p*3;
      sraw[p*4 + c] = src[f];
    }
    __syncthreads();
    for (int i = tid; i < TILE; i += 256) {
      float4 v = spts[i];
      spts[i].w = __fadd_rn(__fadd_rn(__fmul_rn(v.x,v.x), __fmul_rn(v.y,v.y)),
                            __fmul_rn(v.z,v.z));
    }
    __syncthreads();

    for (int c = 0; c < TILE/64; ++c) {
      const float4 cd = spts[c*64 + lane];
      const int cbase = t*TILE + c*64;
#pragma unroll
      for (int qi = 0; qi < QPW; ++qi) {
        float dot = __fadd_rn(__fadd_rn(__fmul_rn(qx[qi],cd.x),
                                        __fmul_rn(qy[qi],cd.y)),
                              __fmul_rn(qz[qi],cd.z));
        float d2 = __fsub_rn(__fadd_rn(qsq[qi], cd.w), __fmul_rn(2.0f, dot));
        unsigned long long m = __ballot(d2 < tau[qi]);
        while (m) {
          const int l = __builtin_ctzll(m);
          m &= (m - 1);
          const float dn = __shfl(d2, l);
          const int   ni_ = cbase + l;
          const float my  = topd[qi];
          const int   myi = topi[qi];
          float ab  = __shfl_up(my, 1);
          int   abi = __shfl_up(myi, 1);
          if (lane == 0) ab = -3e38f;
          const bool ge = dn < my;   // insert at or before this position
          const bool gt = dn < ab;   // insert strictly before -> shift down
          topd[qi] = ge ? (gt ? ab  : dn ) : my;
          topi[qi] = ge ? (gt ? abi : ni_) : myi;
          tau[qi] = __shfl(topd[qi], 15);
        }
      }
    }
  }

#pragma unroll
  for (int qi = 0; qi < QPW; ++qi) {
    if (lane < KNN_K) knn_out[(size_t)(qbase + qi)*KNN_K + lane] = topi[qi];
  }
}

// ---------------------------------------------------------------------------
// Kernel 2: fused Q/K/V projection. 16 rows per block staged in LDS; each
// thread owns one (row, col) and accumulates all three matrices so the LDS
// read of x is amortized 3x. W column reads are coalesced across the wave.
// ---------------------------------------------------------------------------
__global__ __launch_bounds__(256) void qkv_kernel(const float* __restrict__ x,
    const float* __restrict__ Wq, const float* __restrict__ bq,
    const float* __restrict__ Wk, const float* __restrict__ bk,
    const float* __restrict__ Wv, const float* __restrict__ bv,
    float* __restrict__ q, float* __restrict__ k, float* __restrict__ v) {
  __shared__ float xs[16*DIMC];
  const int tid = threadIdx.x;
  const int rowbase = blockIdx.x * 16;
  for (int i = tid; i < 16*DIMC; i += 256) xs[i] = x[(size_t)rowbase*DIMC + i];
  __syncthreads();
  for (int o = tid; o < 16*DIMC; o += 256) {
    const int r = o >> 7, cc = o & 127;
    float aq = bq[cc], ak = bk[cc], av = bv[cc];
    const float* xr = xs + r*DIMC;
#pragma unroll 4
    for (int kk = 0; kk < DIMC; ++kk) {
      const float xv = xr[kk];
      aq = fmaf(xv, Wq[kk*DIMC+cc], aq);
      ak = fmaf(xv, Wk[kk*DIMC+cc], ak);
      av = fmaf(xv, Wv[kk*DIMC+cc], av);
    }
    const size_t oo = (size_t)(rowbase + r)*DIMC + cc;
    q[oo] = aq; k[oo] = ak; v[oo] = av;
  }
}

// ---------------------------------------------------------------------------
// Kernel 3: gather + bias MLP + 4-head/16-neighbor attention.
// 128 threads per point (2 points per 256-block); thread = channel d.
// Each 32-lane group is exactly one head: the QK dot is a width-32
// shfl_xor reduction, softmax is fully register-replicated per lane.
// ---------------------------------------------------------------------------
__global__ __launch_bounds__(256) void attn_kernel(const float* __restrict__ xyz,
    const int* __restrict__ knn, const float* __restrict__ qb,
    const float* __restrict__ kb, const float* __restrict__ vb,
    const float* __restrict__ W1, const float* __restrict__ b1,
    const float* __restrict__ W2, const float* __restrict__ b2,
    float* __restrict__ ao) {
  __shared__ float sbias[2][NH][KNN_K];
  const int tid = threadIdx.x;
  const int pt  = tid >> 7;          // 0..1
  const int d   = tid & 127;         // channel
  const int h   = d >> 5;            // head
  const int p   = blockIdx.x * 2 + pt;
  const int b   = p / NPT;

  int nidx[KNN_K];
#pragma unroll
  for (int j = 0; j < KNN_K; ++j) nidx[j] = knn[(size_t)p*KNN_K + j];

  // bias MLP: 64 threads per point cover (h2, j2)
  if (d < 64) {
    const int h2 = d >> 4, j2 = d & 15;
    const float qx0 = xyz[(size_t)p*3+0];
    const float qy0 = xyz[(size_t)p*3+1];
    const float qz0 = xyz[(size_t)p*3+2];
    const size_t nn = (size_t)(b*NPT + nidx[j2]);
    const float rx = qx0 - xyz[nn*3+0];
    const float ry = qy0 - xyz[nn*3+1];
    const float rz = qz0 - xyz[nn*3+2];
    float acc = b2[h2];
#pragma unroll 4
    for (int u = 0; u < HID; ++u) {
      float hv = rx*W1[0*HID+u] + ry*W1[1*HID+u] + rz*W1[2*HID+u] + b1[u];
      hv = hv > 0.f ? hv : 0.f;
      acc = fmaf(hv, W2[u*NH + h2], acc);
    }
    sbias[pt][h2][j2] = acc;
  }

  const float qd = qb[(size_t)p*DIMC + d];
  float s[KNN_K], vr[KNN_K];
#pragma unroll
  for (int j = 0; j < KNN_K; ++j) {
    const size_t row = ((size_t)(b*NPT + nidx[j]))*DIMC + d;
    float t = qd * kb[row];
    vr[j] = vb[row];
    t += __shfl_xor(t, 1, 32);
    t += __shfl_xor(t, 2, 32);
    t += __shfl_xor(t, 4, 32);
    t += __shfl_xor(t, 8, 32);
    t += __shfl_xor(t, 16, 32);
    s[j] = t;
  }
  __syncthreads();

  const float sc = 0.17677669529663689f; // 1/sqrt(32)
  float mx = -3e38f;
#pragma unroll
  for (int j = 0; j < KNN_K; ++j) {
    s[j] = s[j]*sc + sbias[pt][h][j];
    mx = fmaxf(mx, s[j]);
  }
  float sum = 0.f;
#pragma unroll
  for (int j = 0; j < KNN_K; ++j) { s[j] = expf(s[j]-mx); sum += s[j]; }
  const float inv = 1.f / sum;
  float out = 0.f;
#pragma unroll
  for (int j = 0; j < KNN_K; ++j) out = fmaf(s[j]*inv, vr[j], out);
  ao[(size_t)p*DIMC + d] = out;
}

// ---------------------------------------------------------------------------
// Kernel 4: output projection, IN-PLACE on d_out. Each block stages its own
// 16 rows to LDS before overwriting exactly those rows — no cross-block
// hazard, deterministic.
// ---------------------------------------------------------------------------
__global__ __launch_bounds__(256) void proj_kernel(float* __restrict__ inout,
    const float* __restrict__ Wo, const float* __restrict__ bo) {
  __shared__ float xs[16*DIMC];
  const int tid = threadIdx.x;
  const int rowbase = blockIdx.x * 16;
  for (int i = tid; i < 16*DIMC; i += 256) xs[i] = inout[(size_t)rowbase*DIMC + i];
  __syncthreads();
  for (int o = tid; o < 16*DIMC; o += 256) {
    const int r = o >> 7, cc = o & 127;
    float a = bo[cc];
    const float* xr = xs + r*DIMC;
#pragma unroll 4
    for (int kk = 0; kk < DIMC; ++kk) a = fmaf(xr[kk], Wo[kk*DIMC+cc], a);
    inout[(size_t)(rowbase + r)*DIMC + cc] = a;
  }
}

// ---------------------------------------------------------------------------
extern "C" void kernel_launch(void* const* d_in, const int* in_sizes, int n_in,
                              void* d_out, int out_size, void* d_ws, size_t ws_size,
                              hipStream_t stream) {
  const float* x   = (const float*)d_in[0];
  const float* xyz = (const float*)d_in[1];
  const float* Wq  = (const float*)d_in[2];
  const float* bq  = (const float*)d_in[3];
  const float* Wk  = (const float*)d_in[4];
  const float* bk  = (const float*)d_in[5];
  const float* Wv  = (const float*)d_in[6];
  const float* bv  = (const float*)d_in[7];
  const float* Wo  = (const float*)d_in[8];
  const float* bo  = (const float*)d_in[9];
  const float* W1  = (const float*)d_in[10];
  const float* b1  = (const float*)d_in[11];
  const float* W2  = (const float*)d_in[12];
  const float* b2  = (const float*)d_in[13];
  float* out = (float*)d_out;

  // workspace layout (bytes): knn idx 1MB | q 8MB | k 8MB | v 8MB  => 25MB
  char* ws = (char*)d_ws;
  int*   knn = (int*)ws;
  float* q   = (float*)(ws + (size_t)(1u<<20));
  float* k   = (float*)(ws + (size_t)9*(1u<<20));
  float* v   = (float*)(ws + (size_t)17*(1u<<20));

  hipLaunchKernelGGL(knn_kernel, dim3(BN/(NWV*QPW)), dim3(256), 0, stream, xyz, knn);
  hipLaunchKernelGGL(qkv_kernel, dim3(BN/16), dim3(256), 0, stream,
                     x, Wq, bq, Wk, bk, Wv, bv, q, k, v);
  hipLaunchKernelGGL(attn_kernel, dim3(BN/2), dim3(256), 0, stream,
                     xyz, knn, q, k, v, W1, b1, W2, b2, out);
  hipLaunchKernelGGL(proj_kernel, dim3(BN/16), dim3(256), 0, stream,
                     out, Wo, bo);
}

// Round 4
// 294.719 us; speedup vs baseline: 1.6471x; 1.1135x over previous
//
#include <hip/hip_runtime.h>
#include <hip/hip_bf16.h>
#include <math.h>

#define BATCH 2
#define NPT   8192
#define DIMC  128
#define NH    4
#define HDIM  32
#define KNN_K 16
#define HID   32
#define BN    (BATCH*NPT)   // 16384

// ---------------------------------------------------------------------------
// Kernel 1: exact 16-NN by squared distance.
// One wave owns QPW=2 queries (2048 blocks -> 8 blocks/CU -> 8 waves/SIMD).
// Candidates processed 64/step from an LDS tile storing (2x,2y,2z,sq):
// doubling is exact (exponent bump), so dot2 == 2*dot bit-identically and
// d2 = (qsq+sq) - dot2 matches numpy's sq_i+sq_j-2*dot rounding exactly.
// Running top-16 lives DISTRIBUTED across lanes 0..15 sorted ascending;
// inserts go through a ballot that is RE-PRUNED against the updated tau
// after every insert, so each loop iteration is a genuine insert (the old
// stale-mask version burned 64 serial iterations on the first chunk).
// Strictly-less comparisons keep lower-index-wins tie order == lax.top_k.
// ---------------------------------------------------------------------------
#define TILE 1024
#define QPW  2
#define NWV  4

__global__ __launch_bounds__(256) void knn_kernel(const float* __restrict__ xyz,
                                                  int* __restrict__ knn_out) {
  __shared__ float4 spts[TILE];   // 2x,2y,2z,sq per candidate (16 KB)
  const int tid  = threadIdx.x;
  const int lane = tid & 63;
  const int wave = tid >> 6;
  const int qbase = blockIdx.x * (NWV*QPW) + wave * QPW;  // flat query base
  const int b = qbase / NPT;

  float qx[QPW], qy[QPW], qz[QPW], qsq[QPW];
  float topd[QPW]; int topi[QPW]; float tau[QPW];
#pragma unroll
  for (int qi = 0; qi < QPW; ++qi) {
    const int g = qbase + qi;
    qx[qi] = xyz[(size_t)g*3+0];
    qy[qi] = xyz[(size_t)g*3+1];
    qz[qi] = xyz[(size_t)g*3+2];
    qsq[qi] = __fadd_rn(__fadd_rn(__fmul_rn(qx[qi],qx[qi]),
                                  __fmul_rn(qy[qi],qy[qi])),
                        __fmul_rn(qz[qi],qz[qi]));
    topd[qi] = 3e38f; topi[qi] = 0; tau[qi] = 3e38f;
  }

  for (int t = 0; t < NPT/TILE; ++t) {
    __syncthreads();
    // one lane = one point: 3 scalar loads, exact sq, doubled coords,
    // single ds_write_b128 (bank-conflict-free).
    const float* src = xyz + (size_t)(b*NPT + t*TILE)*3;
    for (int i = tid; i < TILE; i += 256) {
      const float x = src[i*3+0], y = src[i*3+1], z = src[i*3+2];
      const float sq = __fadd_rn(__fadd_rn(__fmul_rn(x,x), __fmul_rn(y,y)),
                                 __fmul_rn(z,z));
      spts[i] = make_float4(x+x, y+y, z+z, sq);
    }
    __syncthreads();

    for (int c = 0; c < TILE/64; ++c) {
      const float4 cd = spts[c*64 + lane];
      const int cbase = t*TILE + c*64;
#pragma unroll
      for (int qi = 0; qi < QPW; ++qi) {
        // dot2 = 2*dot, bit-exact (doubling commutes with rounding)
        float dot2 = __fadd_rn(__fadd_rn(__fmul_rn(qx[qi],cd.x),
                                         __fmul_rn(qy[qi],cd.y)),
                               __fmul_rn(qz[qi],cd.z));
        float d2 = __fsub_rn(__fadd_rn(qsq[qi], cd.w), dot2);
        unsigned long long m = __ballot(d2 < tau[qi]);
        while (m) {
          const int l = __builtin_ctzll(m);
          const float dn = __shfl(d2, l);
          const int   ni_ = cbase + l;
          const float my  = topd[qi];
          const int   myi = topi[qi];
          float ab  = __shfl_up(my, 1);
          int   abi = __shfl_up(myi, 1);
          if (lane == 0) ab = -3e38f;
          const bool ge = dn < my;   // insert at or before this position
          const bool gt = dn < ab;   // insert strictly before -> shift down
          topd[qi] = ge ? (gt ? ab  : dn ) : my;
          topi[qi] = ge ? (gt ? abi : ni_) : myi;
          tau[qi] = __shfl(topd[qi], 15);
          m &= (m - 1);
          if (m) m &= __ballot(d2 < tau[qi]);  // prune stale candidates
        }
      }
    }
  }

#pragma unroll
  for (int qi = 0; qi < QPW; ++qi) {
    if (lane < KNN_K) knn_out[(size_t)(qbase + qi)*KNN_K + lane] = topi[qi];
  }
}

// ---------------------------------------------------------------------------
// Kernel 2: fused Q/K/V projection. 16 rows per block staged in LDS; each
// thread owns one (row, col) and accumulates all three matrices so the LDS
// read of x is amortized 3x. W column reads are coalesced across the wave.
// ---------------------------------------------------------------------------
__global__ __launch_bounds__(256) void qkv_kernel(const float* __restrict__ x,
    const float* __restrict__ Wq, const float* __restrict__ bq,
    const float* __restrict__ Wk, const float* __restrict__ bk,
    const float* __restrict__ Wv, const float* __restrict__ bv,
    float* __restrict__ q, float* __restrict__ k, float* __restrict__ v) {
  __shared__ float xs[16*DIMC];
  const int tid = threadIdx.x;
  const int rowbase = blockIdx.x * 16;
  for (int i = tid; i < 16*DIMC; i += 256) xs[i] = x[(size_t)rowbase*DIMC + i];
  __syncthreads();
  for (int o = tid; o < 16*DIMC; o += 256) {
    const int r = o >> 7, cc = o & 127;
    float aq = bq[cc], ak = bk[cc], av = bv[cc];
    const float* xr = xs + r*DIMC;
#pragma unroll 4
    for (int kk = 0; kk < DIMC; ++kk) {
      const float xv = xr[kk];
      aq = fmaf(xv, Wq[kk*DIMC+cc], aq);
      ak = fmaf(xv, Wk[kk*DIMC+cc], ak);
      av = fmaf(xv, Wv[kk*DIMC+cc], av);
    }
    const size_t oo = (size_t)(rowbase + r)*DIMC + cc;
    q[oo] = aq; k[oo] = ak; v[oo] = av;
  }
}

// ---------------------------------------------------------------------------
// Kernel 3: gather + bias MLP + 4-head/16-neighbor attention.
// 128 threads per point (2 points per 256-block); thread = channel d.
// Each 32-lane group is exactly one head: the QK dot is a width-32
// shfl_xor reduction, softmax is fully register-replicated per lane.
// ---------------------------------------------------------------------------
__global__ __launch_bounds__(256) void attn_kernel(const float* __restrict__ xyz,
    const int* __restrict__ knn, const float* __restrict__ qb,
    const float* __restrict__ kb, const float* __restrict__ vb,
    const float* __restrict__ W1, const float* __restrict__ b1,
    const float* __restrict__ W2, const float* __restrict__ b2,
    float* __restrict__ ao) {
  __shared__ float sbias[2][NH][KNN_K];
  const int tid = threadIdx.x;
  const int pt  = tid >> 7;          // 0..1
  const int d   = tid & 127;         // channel
  const int h   = d >> 5;            // head
  const int p   = blockIdx.x * 2 + pt;
  const int b   = p / NPT;

  int nidx[KNN_K];
#pragma unroll
  for (int j = 0; j < KNN_K; ++j) nidx[j] = knn[(size_t)p*KNN_K + j];

  // bias MLP: 64 threads per point cover (h2, j2)
  if (d < 64) {
    const int h2 = d >> 4, j2 = d & 15;
    const float qx0 = xyz[(size_t)p*3+0];
    const float qy0 = xyz[(size_t)p*3+1];
    const float qz0 = xyz[(size_t)p*3+2];
    const size_t nn = (size_t)(b*NPT + nidx[j2]);
    const float rx = qx0 - xyz[nn*3+0];
    const float ry = qy0 - xyz[nn*3+1];
    const float rz = qz0 - xyz[nn*3+2];
    float acc = b2[h2];
#pragma unroll 4
    for (int u = 0; u < HID; ++u) {
      float hv = rx*W1[0*HID+u] + ry*W1[1*HID+u] + rz*W1[2*HID+u] + b1[u];
      hv = hv > 0.f ? hv : 0.f;
      acc = fmaf(hv, W2[u*NH + h2], acc);
    }
    sbias[pt][h2][j2] = acc;
  }

  const float qd = qb[(size_t)p*DIMC + d];
  float s[KNN_K], vr[KNN_K];
#pragma unroll
  for (int j = 0; j < KNN_K; ++j) {
    const size_t row = ((size_t)(b*NPT + nidx[j]))*DIMC + d;
    float t = qd * kb[row];
    vr[j] = vb[row];
    t += __shfl_xor(t, 1, 32);
    t += __shfl_xor(t, 2, 32);
    t += __shfl_xor(t, 4, 32);
    t += __shfl_xor(t, 8, 32);
    t += __shfl_xor(t, 16, 32);
    s[j] = t;
  }
  __syncthreads();

  const float sc = 0.17677669529663689f; // 1/sqrt(32)
  float mx = -3e38f;
#pragma unroll
  for (int j = 0; j < KNN_K; ++j) {
    s[j] = s[j]*sc + sbias[pt][h][j];
    mx = fmaxf(mx, s[j]);
  }
  float sum = 0.f;
#pragma unroll
  for (int j = 0; j < KNN_K; ++j) { s[j] = expf(s[j]-mx); sum += s[j]; }
  const float inv = 1.f / sum;
  float out = 0.f;
#pragma unroll
  for (int j = 0; j < KNN_K; ++j) out = fmaf(s[j]*inv, vr[j], out);
  ao[(size_t)p*DIMC + d] = out;
}

// ---------------------------------------------------------------------------
// Kernel 4: output projection, IN-PLACE on d_out. Each block stages its own
// 16 rows to LDS before overwriting exactly those rows — no cross-block
// hazard, deterministic.
// ---------------------------------------------------------------------------
__global__ __launch_bounds__(256) void proj_kernel(float* __restrict__ inout,
    const float* __restrict__ Wo, const float* __restrict__ bo) {
  __shared__ float xs[16*DIMC];
  const int tid = threadIdx.x;
  const int rowbase = blockIdx.x * 16;
  for (int i = tid; i < 16*DIMC; i += 256) xs[i] = inout[(size_t)rowbase*DIMC + i];
  __syncthreads();
  for (int o = tid; o < 16*DIMC; o += 256) {
    const int r = o >> 7, cc = o & 127;
    float a = bo[cc];
    const float* xr = xs + r*DIMC;
#pragma unroll 4
    for (int kk = 0; kk < DIMC; ++kk) a = fmaf(xr[kk], Wo[kk*DIMC+cc], a);
    inout[(size_t)(rowbase + r)*DIMC + cc] = a;
  }
}

// ---------------------------------------------------------------------------
extern "C" void kernel_launch(void* const* d_in, const int* in_sizes, int n_in,
                              void* d_out, int out_size, void* d_ws, size_t ws_size,
                              hipStream_t stream) {
  const float* x   = (const float*)d_in[0];
  const float* xyz = (const float*)d_in[1];
  const float* Wq  = (const float*)d_in[2];
  const float* bq  = (const float*)d_in[3];
  const float* Wk  = (const float*)d_in[4];
  const float* bk  = (const float*)d_in[5];
  const float* Wv  = (const float*)d_in[6];
  const float* bv  = (const float*)d_in[7];
  const float* Wo  = (const float*)d_in[8];
  const float* bo  = (const float*)d_in[9];
  const float* W1  = (const float*)d_in[10];
  const float* b1  = (const float*)d_in[11];
  const float* W2  = (const float*)d_in[12];
  const float* b2  = (const float*)d_in[13];
  float* out = (float*)d_out;

  // workspace layout (bytes): knn idx 1MB | q 8MB | k 8MB | v 8MB  => 25MB
  char* ws = (char*)d_ws;
  int*   knn = (int*)ws;
  float* q   = (float*)(ws + (size_t)(1u<<20));
  float* k   = (float*)(ws + (size_t)9*(1u<<20));
  float* v   = (float*)(ws + (size_t)17*(1u<<20));

  hipLaunchKernelGGL(knn_kernel, dim3(BN/(NWV*QPW)), dim3(256), 0, stream, xyz, knn);
  hipLaunchKernelGGL(qkv_kernel, dim3(BN/16), dim3(256), 0, stream,
                     x, Wq, bq, Wk, bk, Wv, bv, q, k, v);
  hipLaunchKernelGGL(attn_kernel, dim3(BN/2), dim3(256), 0, stream,
                     xyz, knn, q, k, v, W1, b1, W2, b2, out);
  hipLaunchKernelGGL(proj_kernel, dim3(BN/16), dim3(256), 0, stream,
                     out, Wo, bo);
}

// Round 5
// 203.011 us; speedup vs baseline: 2.3912x; 1.4517x over previous
//
#include <hip/hip_runtime.h>
#include <hip/hip_bf16.h>
#include <math.h>

#define BATCH 2
#define NPT   8192
#define DIMC  128
#define NH    4
#define KNN_K 16
#define HID   32
#define BN    (BATCH*NPT)   // 16384

// ---------------------------------------------------------------------------
// Kernel 1: exact 16-NN by squared distance.
// One wave owns QPW=2 queries (2048 blocks -> 8 blocks/CU, 32 waves/CU).
// LDS tile stores (2x,2y,2z,sq): doubling is exact, so dot2 == 2*dot
// bit-identically and d2 = (qsq+sq) - dot2 matches numpy's sq_i+sq_j-2*dot
// rounding exactly. Top-16 lives DISTRIBUTED across lanes 0..15 sorted
// ascending; ballot re-pruned after every insert. Insert-path cross-lane
// extraction uses v_readlane (uniform lane index -> SGPR broadcast, no DS
// op, no lgkm wait); only the two shfl_up shifts remain as DS ops and they
// are independent — serial DS chain depth 3 -> 1 per insert.
// Strictly-less comparisons keep lower-index-wins tie order == lax.top_k.
// ---------------------------------------------------------------------------
#define TILE 1024
#define QPW  2
#define NWV  4

__device__ __forceinline__ float readlane_f(float v, int l) {
  return __int_as_float(__builtin_amdgcn_readlane(__float_as_int(v), l));
}

__global__ __launch_bounds__(256) void knn_kernel(const float* __restrict__ xyz,
                                                  int* __restrict__ knn_out) {
  __shared__ float4 spts[TILE];   // 2x,2y,2z,sq per candidate (16 KB)
  const int tid  = threadIdx.x;
  const int lane = tid & 63;
  const int wave = tid >> 6;
  const int qbase = blockIdx.x * (NWV*QPW) + wave * QPW;  // flat query base
  const int b = qbase / NPT;

  float qx[QPW], qy[QPW], qz[QPW], qsq[QPW];
  float topd[QPW]; int topi[QPW]; float tau[QPW];
#pragma unroll
  for (int qi = 0; qi < QPW; ++qi) {
    const int g = qbase + qi;
    qx[qi] = xyz[(size_t)g*3+0];
    qy[qi] = xyz[(size_t)g*3+1];
    qz[qi] = xyz[(size_t)g*3+2];
    qsq[qi] = __fadd_rn(__fadd_rn(__fmul_rn(qx[qi],qx[qi]),
                                  __fmul_rn(qy[qi],qy[qi])),
                        __fmul_rn(qz[qi],qz[qi]));
    topd[qi] = 3e38f; topi[qi] = 0; tau[qi] = 3e38f;
  }

  for (int t = 0; t < NPT/TILE; ++t) {
    __syncthreads();
    // one lane = one point: 3 scalar loads, exact sq, doubled coords,
    // single ds_write_b128 (bank-conflict-free).
    const float* src = xyz + (size_t)(b*NPT + t*TILE)*3;
    for (int i = tid; i < TILE; i += 256) {
      const float x = src[i*3+0], y = src[i*3+1], z = src[i*3+2];
      const float sq = __fadd_rn(__fadd_rn(__fmul_rn(x,x), __fmul_rn(y,y)),
                                 __fmul_rn(z,z));
      spts[i] = make_float4(x+x, y+y, z+z, sq);
    }
    __syncthreads();

    for (int c = 0; c < TILE/64; ++c) {
      const float4 cd = spts[c*64 + lane];
      const int cbase = t*TILE + c*64;
#pragma unroll
      for (int qi = 0; qi < QPW; ++qi) {
        // dot2 = 2*dot, bit-exact (doubling commutes with rounding)
        float dot2 = __fadd_rn(__fadd_rn(__fmul_rn(qx[qi],cd.x),
                                         __fmul_rn(qy[qi],cd.y)),
                               __fmul_rn(qz[qi],cd.z));
        float d2 = __fsub_rn(__fadd_rn(qsq[qi], cd.w), dot2);
        unsigned long long m = __ballot(d2 < tau[qi]);
        while (m) {
          const int l = (int)__builtin_ctzll(m);
          const float dn = readlane_f(d2, l);       // SGPR broadcast, no DS
          const int   ni_ = cbase + l;
          const float my  = topd[qi];
          const int   myi = topi[qi];
          float ab  = __shfl_up(my, 1);             // 2 independent DS ops
          int   abi = __shfl_up(myi, 1);
          if (lane == 0) ab = -3e38f;
          const bool ge = dn < my;   // insert at or before this position
          const bool gt = dn < ab;   // insert strictly before -> shift down
          topd[qi] = ge ? (gt ? ab  : dn ) : my;
          topi[qi] = ge ? (gt ? abi : ni_) : myi;
          tau[qi] = readlane_f(topd[qi], 15);       // SGPR broadcast
          m &= (m - 1);
          if (m) m &= __ballot(d2 < tau[qi]);  // prune stale candidates
        }
      }
    }
  }

#pragma unroll
  for (int qi = 0; qi < QPW; ++qi) {
    if (lane < KNN_K) knn_out[(size_t)(qbase + qi)*KNN_K + lane] = topi[qi];
  }
}

// ---------------------------------------------------------------------------
// float4-component extract (u is compile-time constant in unrolled loops)
// ---------------------------------------------------------------------------
__device__ __forceinline__ float f4c(const float4 v, int u) {
  return u == 0 ? v.x : u == 1 ? v.y : u == 2 ? v.z : v.w;
}

// ---------------------------------------------------------------------------
// Kernel 2: fused Q/K/V projection, register-blocked.
// 16 rows per block in LDS. Thread (cg=tid&31, rg=tid>>5) owns rows
// {rg, rg+8} x cols [4*cg, 4*cg+4) x 3 matrices = 24 accumulators.
// Per kk-quad: 3x4 float4 W loads (shared across both rows), 2 ds_read_b128
// of x, 96 FMA — ~2.4x fewer instructions than the scalar version.
// FMA accumulation order (kk ascending per output) is bit-identical to the
// previous kernel.
// ---------------------------------------------------------------------------
__global__ __launch_bounds__(256) void qkv_kernel(const float* __restrict__ x,
    const float* __restrict__ Wq, const float* __restrict__ bq,
    const float* __restrict__ Wk, const float* __restrict__ bk,
    const float* __restrict__ Wv, const float* __restrict__ bv,
    float* __restrict__ q, float* __restrict__ k, float* __restrict__ v) {
  __shared__ float xs[16*DIMC];
  const int tid = threadIdx.x;
  const int rowbase = blockIdx.x * 16;
  {
    float4* xs4 = (float4*)xs;
    const float4* src4 = (const float4*)(x + (size_t)rowbase*DIMC);
    for (int i = tid; i < 16*DIMC/4; i += 256) xs4[i] = src4[i];
  }
  __syncthreads();

  const int cg = tid & 31, rg = tid >> 5;
  const int c0 = cg * 4;
  float4 aq0 = *(const float4*)&bq[c0], aq1 = aq0;
  float4 ak0 = *(const float4*)&bk[c0], ak1 = ak0;
  float4 av0 = *(const float4*)&bv[c0], av1 = av0;

  for (int kk = 0; kk < DIMC; kk += 4) {
    const float4 xa = *(const float4*)&xs[rg*DIMC + kk];
    const float4 xb = *(const float4*)&xs[(rg+8)*DIMC + kk];
#pragma unroll
    for (int u = 0; u < 4; ++u) {
      const float4 wq = *(const float4*)&Wq[(size_t)(kk+u)*DIMC + c0];
      const float4 wk = *(const float4*)&Wk[(size_t)(kk+u)*DIMC + c0];
      const float4 wv = *(const float4*)&Wv[(size_t)(kk+u)*DIMC + c0];
      const float xau = f4c(xa, u), xbu = f4c(xb, u);
      aq0.x = fmaf(xau, wq.x, aq0.x); aq0.y = fmaf(xau, wq.y, aq0.y);
      aq0.z = fmaf(xau, wq.z, aq0.z); aq0.w = fmaf(xau, wq.w, aq0.w);
      aq1.x = fmaf(xbu, wq.x, aq1.x); aq1.y = fmaf(xbu, wq.y, aq1.y);
      aq1.z = fmaf(xbu, wq.z, aq1.z); aq1.w = fmaf(xbu, wq.w, aq1.w);
      ak0.x = fmaf(xau, wk.x, ak0.x); ak0.y = fmaf(xau, wk.y, ak0.y);
      ak0.z = fmaf(xau, wk.z, ak0.z); ak0.w = fmaf(xau, wk.w, ak0.w);
      ak1.x = fmaf(xbu, wk.x, ak1.x); ak1.y = fmaf(xbu, wk.y, ak1.y);
      ak1.z = fmaf(xbu, wk.z, ak1.z); ak1.w = fmaf(xbu, wk.w, ak1.w);
      av0.x = fmaf(xau, wv.x, av0.x); av0.y = fmaf(xau, wv.y, av0.y);
      av0.z = fmaf(xau, wv.z, av0.z); av0.w = fmaf(xau, wv.w, av0.w);
      av1.x = fmaf(xbu, wv.x, av1.x); av1.y = fmaf(xbu, wv.y, av1.y);
      av1.z = fmaf(xbu, wv.z, av1.z); av1.w = fmaf(xbu, wv.w, av1.w);
    }
  }

  const size_t r0 = (size_t)(rowbase + rg)*DIMC + c0;
  const size_t r1 = (size_t)(rowbase + rg + 8)*DIMC + c0;
  *(float4*)&q[r0] = aq0; *(float4*)&q[r1] = aq1;
  *(float4*)&k[r0] = ak0; *(float4*)&k[r1] = ak1;
  *(float4*)&v[r0] = av0; *(float4*)&v[r1] = av1;
}

// ---------------------------------------------------------------------------
// Kernel 3: gather + bias MLP + 4-head/16-neighbor attention.
// 128 threads per point (2 points per 256-block); thread = channel d.
// Each 32-lane group is exactly one head: the QK dot is a width-32
// shfl_xor reduction, softmax is fully register-replicated per lane.
// ---------------------------------------------------------------------------
__global__ __launch_bounds__(256) void attn_kernel(const float* __restrict__ xyz,
    const int* __restrict__ knn, const float* __restrict__ qb,
    const float* __restrict__ kb, const float* __restrict__ vb,
    const float* __restrict__ W1, const float* __restrict__ b1,
    const float* __restrict__ W2, const float* __restrict__ b2,
    float* __restrict__ ao) {
  __shared__ float sbias[2][NH][KNN_K];
  const int tid = threadIdx.x;
  const int pt  = tid >> 7;          // 0..1
  const int d   = tid & 127;         // channel
  const int h   = d >> 5;            // head
  const int p   = blockIdx.x * 2 + pt;
  const int b   = p / NPT;

  int nidx[KNN_K];
#pragma unroll
  for (int j = 0; j < KNN_K; ++j) nidx[j] = knn[(size_t)p*KNN_K + j];

  // bias MLP: 64 threads per point cover (h2, j2)
  if (d < 64) {
    const int h2 = d >> 4, j2 = d & 15;
    const float qx0 = xyz[(size_t)p*3+0];
    const float qy0 = xyz[(size_t)p*3+1];
    const float qz0 = xyz[(size_t)p*3+2];
    const size_t nn = (size_t)(b*NPT + nidx[j2]);
    const float rx = qx0 - xyz[nn*3+0];
    const float ry = qy0 - xyz[nn*3+1];
    const float rz = qz0 - xyz[nn*3+2];
    float acc = b2[h2];
#pragma unroll 4
    for (int u = 0; u < HID; ++u) {
      float hv = rx*W1[0*HID+u] + ry*W1[1*HID+u] + rz*W1[2*HID+u] + b1[u];
      hv = hv > 0.f ? hv : 0.f;
      acc = fmaf(hv, W2[u*NH + h2], acc);
    }
    sbias[pt][h2][j2] = acc;
  }

  const float qd = qb[(size_t)p*DIMC + d];
  float s[KNN_K], vr[KNN_K];
#pragma unroll
  for (int j = 0; j < KNN_K; ++j) {
    const size_t row = ((size_t)(b*NPT + nidx[j]))*DIMC + d;
    float t = qd * kb[row];
    vr[j] = vb[row];
    t += __shfl_xor(t, 1, 32);
    t += __shfl_xor(t, 2, 32);
    t += __shfl_xor(t, 4, 32);
    t += __shfl_xor(t, 8, 32);
    t += __shfl_xor(t, 16, 32);
    s[j] = t;
  }
  __syncthreads();

  const float sc = 0.17677669529663689f; // 1/sqrt(32)
  float mx = -3e38f;
#pragma unroll
  for (int j = 0; j < KNN_K; ++j) {
    s[j] = s[j]*sc + sbias[pt][h][j];
    mx = fmaxf(mx, s[j]);
  }
  float sum = 0.f;
#pragma unroll
  for (int j = 0; j < KNN_K; ++j) { s[j] = expf(s[j]-mx); sum += s[j]; }
  const float inv = 1.f / sum;
  float out = 0.f;
#pragma unroll
  for (int j = 0; j < KNN_K; ++j) out = fmaf(s[j]*inv, vr[j], out);
  ao[(size_t)p*DIMC + d] = out;
}

// ---------------------------------------------------------------------------
// Kernel 4: output projection, register-blocked, IN-PLACE on d_out. Each
// block stages its own 16 rows to LDS before overwriting exactly those rows.
// ---------------------------------------------------------------------------
__global__ __launch_bounds__(256) void proj_kernel(float* __restrict__ inout,
    const float* __restrict__ Wo, const float* __restrict__ bo) {
  __shared__ float xs[16*DIMC];
  const int tid = threadIdx.x;
  const int rowbase = blockIdx.x * 16;
  {
    float4* xs4 = (float4*)xs;
    const float4* src4 = (const float4*)(inout + (size_t)rowbase*DIMC);
    for (int i = tid; i < 16*DIMC/4; i += 256) xs4[i] = src4[i];
  }
  __syncthreads();

  const int cg = tid & 31, rg = tid >> 5;
  const int c0 = cg * 4;
  float4 a0 = *(const float4*)&bo[c0], a1 = a0;

  for (int kk = 0; kk < DIMC; kk += 4) {
    const float4 xa = *(const float4*)&xs[rg*DIMC + kk];
    const float4 xb = *(const float4*)&xs[(rg+8)*DIMC + kk];
#pragma unroll
    for (int u = 0; u < 4; ++u) {
      const float4 w = *(const float4*)&Wo[(size_t)(kk+u)*DIMC + c0];
      const float xau = f4c(xa, u), xbu = f4c(xb, u);
      a0.x = fmaf(xau, w.x, a0.x); a0.y = fmaf(xau, w.y, a0.y);
      a0.z = fmaf(xau, w.z, a0.z); a0.w = fmaf(xau, w.w, a0.w);
      a1.x = fmaf(xbu, w.x, a1.x); a1.y = fmaf(xbu, w.y, a1.y);
      a1.z = fmaf(xbu, w.z, a1.z); a1.w = fmaf(xbu, w.w, a1.w);
    }
  }

  *(float4*)&inout[(size_t)(rowbase + rg)*DIMC + c0]     = a0;
  *(float4*)&inout[(size_t)(rowbase + rg + 8)*DIMC + c0] = a1;
}

// ---------------------------------------------------------------------------
extern "C" void kernel_launch(void* const* d_in, const int* in_sizes, int n_in,
                              void* d_out, int out_size, void* d_ws, size_t ws_size,
                              hipStream_t stream) {
  const float* x   = (const float*)d_in[0];
  const float* xyz = (const float*)d_in[1];
  const float* Wq  = (const float*)d_in[2];
  const float* bq  = (const float*)d_in[3];
  const float* Wk  = (const float*)d_in[4];
  const float* bk  = (const float*)d_in[5];
  const float* Wv  = (const float*)d_in[6];
  const float* bv  = (const float*)d_in[7];
  const float* Wo  = (const float*)d_in[8];
  const float* bo  = (const float*)d_in[9];
  const float* W1  = (const float*)d_in[10];
  const float* b1  = (const float*)d_in[11];
  const float* W2  = (const float*)d_in[12];
  const float* b2  = (const float*)d_in[13];
  float* out = (float*)d_out;

  // workspace layout (bytes): knn idx 1MB | q 8MB | k 8MB | v 8MB  => 25MB
  char* ws = (char*)d_ws;
  int*   knn = (int*)ws;
  float* q   = (float*)(ws + (size_t)(1u<<20));
  float* k   = (float*)(ws + (size_t)9*(1u<<20));
  float* v   = (float*)(ws + (size_t)17*(1u<<20));

  hipLaunchKernelGGL(knn_kernel, dim3(BN/(NWV*QPW)), dim3(256), 0, stream, xyz, knn);
  hipLaunchKernelGGL(qkv_kernel, dim3(BN/16), dim3(256), 0, stream,
                     x, Wq, bq, Wk, bk, Wv, bv, q, k, v);
  hipLaunchKernelGGL(attn_kernel, dim3(BN/2), dim3(256), 0, stream,
                     xyz, knn, q, k, v, W1, b1, W2, b2, out);
  hipLaunchKernelGGL(proj_kernel, dim3(BN/16), dim3(256), 0, stream,
                     out, Wo, bo);
}